// Round 1
// 86.522 us; speedup vs baseline: 1.0014x; 1.0014x over previous
//
#include <hip/hip_runtime.h>

#define NSTEP 39                 // K = 39*32 = 1248 slots
#define NCOL  (NSTEP * 8)        // 312 feature columns; packed in PAIRS (156 packs)

typedef _Float16 half8   __attribute__((ext_vector_type(8)));
typedef __fp16   f16x2   __attribute__((ext_vector_type(2)));
typedef __fp16   f16x4   __attribute__((ext_vector_type(4)));
typedef __fp16   f16x8   __attribute__((ext_vector_type(8)));
typedef float    float4v __attribute__((ext_vector_type(4)));

// Column table, ordered so columns (2j, 2j+1) form a v_pk_mul_f16-friendly
// pair (same mode, same o). Per column c, 4 features (q = 0..3):
//   mode 3: x_a * x_b * x_{o+q}  (valid iff o+q >= a; a <= o+3)
//   mode 2: x_a * x_{o+q}        (valid iff o+q <= a; a >= o)
//   mode 1: x_{o+q}              (always valid; +identity folded in W)
//   mode 4: 1.0                  (valid iff q == 0)
//   mode 0: pad (W row zero)
// Invalid slots are zeroed on the W side; A side computes finite garbage * 0.
struct Cols { short mode[NCOL]; short a[NCOL]; short b[NCOL]; short o[NCOL]; };
static constexpr Cols mk_cols() {
  Cols c{};
  int k = 0;
  // specials: 4x deg-1, 1x const, 1x pad  (3 packs)
  for (int o = 0; o < 16; o += 4) { c.mode[k] = 1; c.o[k] = (short)o; ++k; }
  c.mode[k] = 4; ++k;
  c.mode[k] = 0; ++k;
  // deg-2: for o, a = o..15 -> pairs (a, a+1) with a even, A-pack = x2[a/2]
  for (int o = 0; o < 16; o += 4)
    for (int a = o; a < 16; ++a) { c.mode[k] = 2; c.a[k] = (short)a; c.o[k] = (short)o; ++k; }
  // deg-3: per o, regular pairs (a,b),(a,b+1) b even, then leftover (a,a) evens
  for (int o = 0; o < 16; o += 4) {
    const int amax = (o + 3 < 15) ? o + 3 : 15;
    for (int a = 0; a <= amax; ++a)
      for (int b = 0; b + 1 <= a; b += 2) {
        c.mode[k] = 3; c.a[k] = (short)a; c.b[k] = (short)b;     c.o[k] = (short)o; ++k;
        c.mode[k] = 3; c.a[k] = (short)a; c.b[k] = (short)(b+1); c.o[k] = (short)o; ++k;
      }
    for (int a = 0; a <= amax; a += 2) {
      c.mode[k] = 3; c.a[k] = (short)a; c.b[k] = (short)a; c.o[k] = (short)o; ++k;
    }
  }
  for (; k < NCOL; ++k) c.mode[k] = 0;    // pad cols
  return c;
}
static constexpr Cols COLS = mk_cols();

// ---- Pre-kernel: f16 W fragments (permutation + validity zeroing + identity
// fold) into d_ws. Entry e = (step, q, n): 8 halfs = B[k=step*32+q*8+j][n].
__global__ void build_wfrag(const float* __restrict__ W, _Float16* __restrict__ Wp) {
  const int e = blockIdx.x * 256 + threadIdx.x;
  if (e >= NSTEP * 64) return;
  const int step = e >> 6;
  const int q    = (e >> 4) & 3;
  const int n    = e & 15;
  half8 hv;
  #pragma unroll
  for (int j = 0; j < 8; ++j) {
    const int c = step * 8 + j;
    const int mode = COLS.mode[c], a = COLS.a[c], b = COLS.b[c], o = COLS.o[c];
    float v = 0.0f;
    if (mode == 3) {
      const int i = o + q;                      // i <= 15 guaranteed
      if (i >= a) v = W[(153 + i * (i + 1) * (i + 2) / 6 + a * (a + 1) / 2 + b) * 16 + n];
    } else if (mode == 2) {
      const int bb = o + q;
      if (bb <= a) v = W[(17 + a * (a + 1) / 2 + bb) * 16 + n];
    } else if (mode == 1) {
      const int i = o + q;
      v = W[(1 + i) * 16 + n];
      if (i == n) v += 1.0f;                    // fold residual: out = x + poly@W
    } else if (mode == 4) {
      if (q == 0) v = W[n];
    }
    hv[j] = (_Float16)v;
  }
  *(half8*)(Wp + e * 8) = hv;
}

// Packed pair of features (cols C, C+1), C even. x2[r] = (x_{2r}, x_{2r+1});
// w2[j] = (x_{4j+q}, x_{4j+q}) broadcast.
template<int C>
__device__ __forceinline__ f16x2 colpair(const f16x2 (&x2)[8], const f16x2 (&w2)[4]) {
  constexpr int m0 = COLS.mode[C], m1 = COLS.mode[C + 1];
  if constexpr (m0 == 3 && COLS.a[C] == COLS.b[C]) {
    // leftover pair: (x_{a1}^2, x_{a2}^2) * w
    constexpr int a1 = COLS.a[C], a2 = COLS.a[C + 1];
    const f16x2 s = __builtin_shufflevector(x2[a1 / 2], x2[a2 / 2], a1 % 2, 2 + a2 % 2);
    return (s * s) * w2[COLS.o[C] >> 2];
  } else if constexpr (m0 == 3) {
    // regular pair: x_a * (x_b, x_{b+1}) * w   (b even; xa broadcast = op_sel)
    constexpr int a = COLS.a[C], b = COLS.b[C];
    const f16x2 xa = __builtin_shufflevector(x2[a / 2], x2[a / 2], a % 2, a % 2);
    return (xa * x2[b / 2]) * w2[COLS.o[C] >> 2];
  } else if constexpr (m0 == 2) {
    // pair: (x_a, x_{a+1}) * w   (a even, so x2[a/2] is the pack)
    return x2[COLS.a[C] / 2] * w2[COLS.o[C] >> 2];
  } else if constexpr (m0 == 1 && m1 == 1) {
    // (w_{o1+q}, w_{o2+q})
    return __builtin_shufflevector(w2[COLS.o[C] >> 2], w2[COLS.o[C + 1] >> 2], 0, 2);
  } else if constexpr (m0 == 4) {
    return (f16x2){(__fp16)1.0f, (__fp16)0.0f};
  } else {
    return (f16x2){(__fp16)0.0f, (__fp16)0.0f};
  }
}

// MFMA chain over all K-steps; B fragments come straight from registers.
template<int S>
__device__ __forceinline__ void steps(const half8 (&bfr)[NSTEP],
                                      const f16x2 (&x2)[8], const f16x2 (&w2)[4],
                                      float4v& acc) {
  if constexpr (S < NSTEP) {
    const f16x2 p01 = colpair<S * 8 + 0>(x2, w2);
    const f16x2 p23 = colpair<S * 8 + 2>(x2, w2);
    const f16x2 p45 = colpair<S * 8 + 4>(x2, w2);
    const f16x2 p67 = colpair<S * 8 + 6>(x2, w2);
    const f16x4 lo = __builtin_shufflevector(p01, p23, 0, 1, 2, 3);
    const f16x4 hi = __builtin_shufflevector(p45, p67, 0, 1, 2, 3);
    const f16x8 a8 = __builtin_shufflevector(lo, hi, 0, 1, 2, 3, 4, 5, 6, 7);
    const half8 af = __builtin_bit_cast(half8, a8);
    acc = __builtin_amdgcn_mfma_f32_16x16x32_f16(af, bfr[S], acc, 0, 0, 0);
    steps<S + 1>(bfr, x2, w2, acc);
  }
}

// Persistent-wave version: NO LDS. Each wave loads all 39 B-fragments into
// registers once (39*4 = 156 VGPR; W is tile-invariant) and loops over 8
// row-tiles, prefetching the next tile's x during the current MFMA chain.
// ~215 VGPR -> 2 waves/SIMD (8 waves/CU); grid 512 x 256thr fills the chip
// exactly once (2 blocks/CU). Removes the old per-CU ~12.5us ds_read_b128
// serialization + staging + barriers.
__global__ __launch_bounds__(256, 2)
void taylor_fwd(const float* __restrict__ X, const _Float16* __restrict__ Wp,
                float* __restrict__ O, const int ntiles) {
  const int tid  = threadIdx.x;
  const int lane = tid & 63;
  const int m    = lane & 15;
  const int q    = lane >> 4;
  const int wid  = blockIdx.x * 4 + (tid >> 6);
  const int nw   = gridDim.x * 4;

  // B fragments: global -> registers, once per wave (coalesced 16B/lane).
  half8 bfr[NSTEP];
  {
    const _Float16* wpq = Wp + (size_t)(q * 16 + m) * 8;
    #pragma unroll
    for (int S = 0; S < NSTEP; ++S)
      bfr[S] = *(const half8*)(wpq + S * 512);
  }

  // lane-invariant v_perm selector: w2[j] = broadcast of x_{4j+q}
  // bytes of (x2[2j+1]:x2[2j]): sel 0-3 -> x2[2j], 4-7 -> x2[2j+1]
  const unsigned psel = 0x01000100u + (unsigned)q * 0x02020202u;

  int tile = wid;
  float4v xv[4];
  if (tile < ntiles) {
    const float4v* xp = (const float4v*)(X + (size_t)(tile * 16 + m) * 16);
    #pragma unroll
    for (int c = 0; c < 4; ++c) xv[c] = xp[c];
  }

  while (tile < ntiles) {
    const int next = tile + nw;

    // convert current row to packed f16 (x2[r] = (x_{2r}, x_{2r+1}))
    f16x2 x2[8];
    #pragma unroll
    for (int c4 = 0; c4 < 4; ++c4) {
      x2[c4 * 2 + 0] = __builtin_amdgcn_cvt_pkrtz(xv[c4][0], xv[c4][1]);
      x2[c4 * 2 + 1] = __builtin_amdgcn_cvt_pkrtz(xv[c4][2], xv[c4][3]);
    }

    // prefetch next tile's x — issues global loads that retire under the MFMA chain
    float4v xn[4];
    if (next < ntiles) {
      const float4v* xp = (const float4v*)(X + (size_t)(next * 16 + m) * 16);
      #pragma unroll
      for (int c = 0; c < 4; ++c) xn[c] = xp[c];
    } else {
      #pragma unroll
      for (int c = 0; c < 4; ++c) xn[c] = (float4v){0.f, 0.f, 0.f, 0.f};
    }

    // branchless w2: one v_perm_b32 per pack (replaces 4-way divergent setw2)
    f16x2 w2[4];
    #pragma unroll
    for (int j = 0; j < 4; ++j) {
      const unsigned r = __builtin_amdgcn_perm(
          __builtin_bit_cast(unsigned, x2[2 * j + 1]),
          __builtin_bit_cast(unsigned, x2[2 * j]), psel);
      w2[j] = __builtin_bit_cast(f16x2, r);
    }

    float4v acc = (float4v){0.f, 0.f, 0.f, 0.f};
    steps<0>(bfr, x2, w2, acc);

    // Epilogue: C/D layout col(n) = lane&15, row = q*4 + reg
    const int rb = tile * 16;
    #pragma unroll
    for (int r = 0; r < 4; ++r) {
      const int row = rb + q * 4 + r;
      O[(size_t)row * 16 + m] = acc[r];
    }

    #pragma unroll
    for (int c = 0; c < 4; ++c) xv[c] = xn[c];
    tile = next;
  }
}

extern "C" void kernel_launch(void* const* d_in, const int* in_sizes, int n_in,
                              void* d_out, int out_size, void* d_ws, size_t ws_size,
                              hipStream_t stream) {
  const float* X = (const float*)d_in[0];
  const float* W = (const float*)d_in[1];
  float*       O = (float*)d_out;
  _Float16*    Wp = (_Float16*)d_ws;               // NSTEP*64*16 B = 39936 B
  const int batch  = in_sizes[0] / 16;             // 262144
  const int ntiles = batch / 16;                   // 16384 wave-tiles
  const int grid   = 512;                          // 2048 waves, 8 tiles/wave

  build_wfrag<<<(NSTEP * 64 + 255) / 256, 256, 0, stream>>>(W, Wp);
  taylor_fwd<<<grid, 256, 0, stream>>>(X, Wp, O, ntiles);
}

// Round 2
// 84.992 us; speedup vs baseline: 1.0194x; 1.0180x over previous
//
#include <hip/hip_runtime.h>

#define NSTEP 39                 // K = 39*32 = 1248 slots
#define NCOL  (NSTEP * 8)        // 312 feature columns; packed in PAIRS (156 packs)

typedef _Float16 half8   __attribute__((ext_vector_type(8)));
typedef __fp16   f16x2   __attribute__((ext_vector_type(2)));
typedef __fp16   f16x4   __attribute__((ext_vector_type(4)));
typedef __fp16   f16x8   __attribute__((ext_vector_type(8)));
typedef float    float4v __attribute__((ext_vector_type(4)));

// Column table, ordered so columns (2j, 2j+1) form a v_pk_mul_f16-friendly
// pair (same mode, same o). Per column c, 4 features (q = 0..3):
//   mode 3: x_a * x_b * x_{o+q}  (valid iff o+q >= a; a <= o+3)
//   mode 2: x_a * x_{o+q}        (valid iff o+q <= a; a >= o)
//   mode 1: x_{o+q}              (always valid; +identity folded in W)
//   mode 4: 1.0                  (valid iff q == 0)
//   mode 0: pad (W side zero)
// Invalid slots are zeroed on the W side; A side computes finite garbage * 0.
struct Cols { short mode[NCOL]; short a[NCOL]; short b[NCOL]; short o[NCOL]; };
static constexpr Cols mk_cols() {
  Cols c{};
  int k = 0;
  // specials: 4x deg-1, 1x const, 1x pad  (3 packs)
  for (int o = 0; o < 16; o += 4) { c.mode[k] = 1; c.o[k] = (short)o; ++k; }
  c.mode[k] = 4; ++k;
  c.mode[k] = 0; ++k;
  // deg-2: for o, a = o..15 -> pairs (a, a+1) with a even, A-pack = x2[a/2]
  for (int o = 0; o < 16; o += 4)
    for (int a = o; a < 16; ++a) { c.mode[k] = 2; c.a[k] = (short)a; c.o[k] = (short)o; ++k; }
  // deg-3: per o, regular pairs (a,b),(a,b+1) b even, then leftover (a,a) evens
  for (int o = 0; o < 16; o += 4) {
    const int amax = (o + 3 < 15) ? o + 3 : 15;
    for (int a = 0; a <= amax; ++a)
      for (int b = 0; b + 1 <= a; b += 2) {
        c.mode[k] = 3; c.a[k] = (short)a; c.b[k] = (short)b;     c.o[k] = (short)o; ++k;
        c.mode[k] = 3; c.a[k] = (short)a; c.b[k] = (short)(b+1); c.o[k] = (short)o; ++k;
      }
    for (int a = 0; a <= amax; a += 2) {
      c.mode[k] = 3; c.a[k] = (short)a; c.b[k] = (short)a; c.o[k] = (short)o; ++k;
    }
  }
  for (; k < NCOL; ++k) c.mode[k] = 0;    // pad cols
  return c;
}
static constexpr Cols COLS = mk_cols();

// ---- In-kernel W-fragment gather (replaces the build_wfrag pre-kernel and
// all d_ws traffic). One element of lane (q, m)'s B fragment for column C:
// B[k][n] with n = m, k = step*32 + q*8 + (C%8). All column metadata is
// compile-time; index formulas always land in [0, 969*16) even for invalid
// (q, column) combos, so we load unconditionally and zero via cndmask.
template<int C>
__device__ __forceinline__ _Float16 wfrag_elem(const float* __restrict__ W,
                                               const int q, const int m) {
  constexpr int mode = COLS.mode[C], a = COLS.a[C], b = COLS.b[C], o = COLS.o[C];
  if constexpr (mode == 3) {
    const int i = o + q;                       // i <= 15
    const float lv = W[(153 + i * (i + 1) * (i + 2) / 6 + a * (a + 1) / 2 + b) * 16 + m];
    if constexpr (a > o)   return (_Float16)((i >= a) ? lv : 0.0f);
    else                   return (_Float16)lv;          // q >= 0 >= a-o: always valid
  } else if constexpr (mode == 2) {
    const int bb = o + q;
    const float lv = W[(17 + a * (a + 1) / 2 + bb) * 16 + m];
    if constexpr (a - o < 3) return (_Float16)((bb <= a) ? lv : 0.0f);
    else                     return (_Float16)lv;        // q <= 3 <= a-o: always valid
  } else if constexpr (mode == 1) {
    const int i = o + q;
    float lv = W[(1 + i) * 16 + m];
    lv += (i == m) ? 1.0f : 0.0f;              // fold residual: out = x + poly@W
    return (_Float16)lv;
  } else if constexpr (mode == 4) {
    return (_Float16)((q == 0) ? W[m] : 0.0f);
  } else {
    return (_Float16)0.0f;
  }
}

template<int S>
__device__ __forceinline__ void gather_b(const float* __restrict__ W,
                                         const int q, const int m,
                                         half8 (&bfr)[NSTEP]) {
  if constexpr (S < NSTEP) {
    half8 hv;
    hv[0] = wfrag_elem<S * 8 + 0>(W, q, m);
    hv[1] = wfrag_elem<S * 8 + 1>(W, q, m);
    hv[2] = wfrag_elem<S * 8 + 2>(W, q, m);
    hv[3] = wfrag_elem<S * 8 + 3>(W, q, m);
    hv[4] = wfrag_elem<S * 8 + 4>(W, q, m);
    hv[5] = wfrag_elem<S * 8 + 5>(W, q, m);
    hv[6] = wfrag_elem<S * 8 + 6>(W, q, m);
    hv[7] = wfrag_elem<S * 8 + 7>(W, q, m);
    bfr[S] = hv;
    gather_b<S + 1>(W, q, m, bfr);
  }
}

// Packed pair of features (cols C, C+1), C even. x2[r] = (x_{2r}, x_{2r+1});
// w2[j] = (x_{4j+q}, x_{4j+q}) broadcast.
template<int C>
__device__ __forceinline__ f16x2 colpair(const f16x2 (&x2)[8], const f16x2 (&w2)[4]) {
  constexpr int m0 = COLS.mode[C], m1 = COLS.mode[C + 1];
  if constexpr (m0 == 3 && COLS.a[C] == COLS.b[C]) {
    // leftover pair: (x_{a1}^2, x_{a2}^2) * w
    constexpr int a1 = COLS.a[C], a2 = COLS.a[C + 1];
    const f16x2 s = __builtin_shufflevector(x2[a1 / 2], x2[a2 / 2], a1 % 2, 2 + a2 % 2);
    return (s * s) * w2[COLS.o[C] >> 2];
  } else if constexpr (m0 == 3) {
    // regular pair: x_a * (x_b, x_{b+1}) * w   (b even; xa broadcast = op_sel)
    constexpr int a = COLS.a[C], b = COLS.b[C];
    const f16x2 xa = __builtin_shufflevector(x2[a / 2], x2[a / 2], a % 2, a % 2);
    return (xa * x2[b / 2]) * w2[COLS.o[C] >> 2];
  } else if constexpr (m0 == 2) {
    // pair: (x_a, x_{a+1}) * w   (a even, so x2[a/2] is the pack)
    return x2[COLS.a[C] / 2] * w2[COLS.o[C] >> 2];
  } else if constexpr (m0 == 1 && m1 == 1) {
    // (w_{o1+q}, w_{o2+q})
    return __builtin_shufflevector(w2[COLS.o[C] >> 2], w2[COLS.o[C + 1] >> 2], 0, 2);
  } else if constexpr (m0 == 4) {
    return (f16x2){(__fp16)1.0f, (__fp16)0.0f};
  } else {
    return (f16x2){(__fp16)0.0f, (__fp16)0.0f};
  }
}

// MFMA chain over all K-steps; B fragments come straight from registers.
template<int S>
__device__ __forceinline__ void steps(const half8 (&bfr)[NSTEP],
                                      const f16x2 (&x2)[8], const f16x2 (&w2)[4],
                                      float4v& acc) {
  if constexpr (S < NSTEP) {
    const f16x2 p01 = colpair<S * 8 + 0>(x2, w2);
    const f16x2 p23 = colpair<S * 8 + 2>(x2, w2);
    const f16x2 p45 = colpair<S * 8 + 4>(x2, w2);
    const f16x2 p67 = colpair<S * 8 + 6>(x2, w2);
    const f16x4 lo = __builtin_shufflevector(p01, p23, 0, 1, 2, 3);
    const f16x4 hi = __builtin_shufflevector(p45, p67, 0, 1, 2, 3);
    const f16x8 a8 = __builtin_shufflevector(lo, hi, 0, 1, 2, 3, 4, 5, 6, 7);
    const half8 af = __builtin_bit_cast(half8, a8);
    acc = __builtin_amdgcn_mfma_f32_16x16x32_f16(af, bfr[S], acc, 0, 0, 0);
    steps<S + 1>(bfr, x2, w2, acc);
  }
}

// Single-dispatch persistent-wave version: NO LDS, NO d_ws, NO pre-kernel.
// Each wave gathers its 39 B-fragments straight from W (62 KB, L2-resident;
// ~312 one-time scalar loads, validity via cndmask), then loops over 8
// row-tiles prefetching the next tile's x under the MFMA chain.
// ~220 VGPR -> 2 waves/SIMD (8/CU); grid 512 x 256thr = 2 blocks/CU.
__global__ __launch_bounds__(256, 2)
void taylor_fwd(const float* __restrict__ X, const float* __restrict__ W,
                float* __restrict__ O, const int ntiles) {
  const int tid  = threadIdx.x;
  const int lane = tid & 63;
  const int m    = lane & 15;
  const int q    = lane >> 4;
  const int wid  = blockIdx.x * 4 + (tid >> 6);
  const int nw   = gridDim.x * 4;

  // B fragments: gathered from W into registers, once per wave.
  half8 bfr[NSTEP];
  gather_b<0>(W, q, m, bfr);

  // lane-invariant v_perm selector: w2[j] = broadcast of x_{4j+q}
  // bytes of (x2[2j+1]:x2[2j]): sel 0-3 -> x2[2j], 4-7 -> x2[2j+1]
  const unsigned psel = 0x01000100u + (unsigned)q * 0x02020202u;

  int tile = wid;
  float4v xv[4];
  if (tile < ntiles) {
    const float4v* xp = (const float4v*)(X + (size_t)(tile * 16 + m) * 16);
    #pragma unroll
    for (int c = 0; c < 4; ++c) xv[c] = xp[c];
  }

  while (tile < ntiles) {
    const int next = tile + nw;

    // convert current row to packed f16 (x2[r] = (x_{2r}, x_{2r+1}))
    f16x2 x2[8];
    #pragma unroll
    for (int c4 = 0; c4 < 4; ++c4) {
      x2[c4 * 2 + 0] = __builtin_amdgcn_cvt_pkrtz(xv[c4][0], xv[c4][1]);
      x2[c4 * 2 + 1] = __builtin_amdgcn_cvt_pkrtz(xv[c4][2], xv[c4][3]);
    }

    // prefetch next tile's x — global loads retire under the MFMA chain
    float4v xn[4];
    if (next < ntiles) {
      const float4v* xp = (const float4v*)(X + (size_t)(next * 16 + m) * 16);
      #pragma unroll
      for (int c = 0; c < 4; ++c) xn[c] = xp[c];
    } else {
      #pragma unroll
      for (int c = 0; c < 4; ++c) xn[c] = (float4v){0.f, 0.f, 0.f, 0.f};
    }

    // branchless w2: one v_perm_b32 per pack
    f16x2 w2[4];
    #pragma unroll
    for (int j = 0; j < 4; ++j) {
      const unsigned r = __builtin_amdgcn_perm(
          __builtin_bit_cast(unsigned, x2[2 * j + 1]),
          __builtin_bit_cast(unsigned, x2[2 * j]), psel);
      w2[j] = __builtin_bit_cast(f16x2, r);
    }

    float4v acc = (float4v){0.f, 0.f, 0.f, 0.f};
    steps<0>(bfr, x2, w2, acc);

    // Epilogue: C/D layout col(n) = lane&15, row = q*4 + reg
    const int rb = tile * 16;
    #pragma unroll
    for (int r = 0; r < 4; ++r) {
      const int row = rb + q * 4 + r;
      O[(size_t)row * 16 + m] = acc[r];
    }

    #pragma unroll
    for (int c = 0; c < 4; ++c) xv[c] = xn[c];
    tile = next;
  }
}

extern "C" void kernel_launch(void* const* d_in, const int* in_sizes, int n_in,
                              void* d_out, int out_size, void* d_ws, size_t ws_size,
                              hipStream_t stream) {
  const float* X = (const float*)d_in[0];
  const float* W = (const float*)d_in[1];
  float*       O = (float*)d_out;
  (void)d_ws; (void)ws_size;                       // workspace intentionally unused
  const int batch  = in_sizes[0] / 16;             // 262144
  const int ntiles = batch / 16;                   // 16384 wave-tiles
  const int grid   = 512;                          // 2048 waves, 8 tiles/wave

  taylor_fwd<<<grid, 256, 0, stream>>>(X, W, O, ntiles);
}